// Round 1
// baseline (94.144 us; speedup 1.0000x reference)
//
#include <hip/hip_runtime.h>
#include <math.h>

// Problem constants (fixed by setup_inputs): N=4096 rows, C=32000 cols, f32.
#define ROWS      4096
#define COLS      32000
#define COLS4     8000          // COLS / 4 (float4 count per row)
#define BLK       1024
#define NWAVES    (BLK / 64)
#define K_ITERS   8             // ceil(COLS4 / BLK) = ceil(8000/1024)

#define S_SCALE   30.0f
#define COS_M     0.95533648912560601964f   // cos(0.3)
#define SIN_M     0.29552020666133957511f   // sin(0.3)

// One block per row. Row slice lives in registers (8 x float4 per thread):
// pass 1 computes sum(x^2) while loading, pass 2 re-reads registers for
// sum(exp(S*x/norm)). x is read from HBM exactly once.
__global__ void arcface_row_kernel(const float* __restrict__ x,
                                   const int* __restrict__ target,
                                   float* __restrict__ rowL) {
    const int row = blockIdx.x;
    const int tid = threadIdx.x;
    const int lane = tid & 63;
    const int wave = tid >> 6;

    const float4* __restrict__ rowp =
        reinterpret_cast<const float4*>(x + (size_t)row * COLS);

    __shared__ float red[NWAVES];
    __shared__ float s_inv;

    // ---- pass 1: load row into registers, accumulate sum of squares ----
    float4 v[K_ITERS];
    float ss = 0.0f;
    #pragma unroll
    for (int k = 0; k < K_ITERS; ++k) {
        const int idx = k * BLK + tid;
        if (idx < COLS4) {
            v[k] = rowp[idx];
            ss += v[k].x * v[k].x + v[k].y * v[k].y
                + v[k].z * v[k].z + v[k].w * v[k].w;
        }
    }

    // block reduce ss
    #pragma unroll
    for (int off = 32; off > 0; off >>= 1) ss += __shfl_down(ss, off, 64);
    if (lane == 0) red[wave] = ss;
    __syncthreads();
    if (tid == 0) {
        float tot = 0.0f;
        #pragma unroll
        for (int w = 0; w < NWAVES; ++w) tot += red[w];
        const float norm = sqrtf(tot);
        s_inv = 1.0f / fmaxf(norm, 1e-12f);
    }
    __syncthreads();
    const float inv = s_inv;
    const float sinv = S_SCALE * inv;

    // ---- pass 2: sum of exp(S * x / norm) from registers ----
    float es = 0.0f;
    #pragma unroll
    for (int k = 0; k < K_ITERS; ++k) {
        const int idx = k * BLK + tid;
        if (idx < COLS4) {
            es += __expf(sinv * v[k].x) + __expf(sinv * v[k].y)
                + __expf(sinv * v[k].z) + __expf(sinv * v[k].w);
        }
    }
    #pragma unroll
    for (int off = 32; off > 0; off >>= 1) es += __shfl_down(es, off, 64);
    if (lane == 0) red[wave] = es;   // safe: prior reads of red[] completed
    __syncthreads();                 // before the s_inv barrier above

    if (tid == 0) {
        float row_sum = 0.0f;
        #pragma unroll
        for (int w = 0; w < NWAVES; ++w) row_sum += red[w];

        const int   tgt   = target[row];
        const float xt    = x[(size_t)row * COLS + tgt];
        const float cos_t = xt * inv;

        // numerator = S * cos(acos(clamp(cos_t)) + M), trig-free form
        const float c = fminf(fmaxf(cos_t, -1.0f + 1e-7f), 1.0f - 1e-7f);
        const float sin_t = sqrtf(fmaxf(1.0f - c * c, 0.0f));
        const float numerator = S_SCALE * (c * COS_M - sin_t * SIN_M);

        const float denom = __expf(numerator) + row_sum - __expf(S_SCALE * cos_t);
        rowL[row] = numerator - logf(denom);
    }
}

// Single-block final reduction: out = -mean(rowL)
__global__ void arcface_final_kernel(const float* __restrict__ rowL,
                                     float* __restrict__ out) {
    __shared__ float red[4];
    const int tid = threadIdx.x;
    float s = 0.0f;
    for (int i = tid; i < ROWS; i += 256) s += rowL[i];
    #pragma unroll
    for (int off = 32; off > 0; off >>= 1) s += __shfl_down(s, off, 64);
    if ((tid & 63) == 0) red[tid >> 6] = s;
    __syncthreads();
    if (tid == 0) {
        const float tot = red[0] + red[1] + red[2] + red[3];
        out[0] = -(tot / (float)ROWS);
    }
}

extern "C" void kernel_launch(void* const* d_in, const int* in_sizes, int n_in,
                              void* d_out, int out_size, void* d_ws, size_t ws_size,
                              hipStream_t stream) {
    const float* x      = (const float*)d_in[0];
    const int*   target = (const int*)d_in[1];
    float*       out    = (float*)d_out;
    float*       rowL   = (float*)d_ws;   // ROWS floats = 16 KB scratch

    arcface_row_kernel<<<ROWS, BLK, 0, stream>>>(x, target, rowL);
    arcface_final_kernel<<<1, 256, 0, stream>>>(rowL, out);
}

// Round 3
// 82.434 us; speedup vs baseline: 1.1420x; 1.1420x over previous
//
#include <hip/hip_runtime.h>
#include <math.h>

// Problem constants (fixed by setup_inputs): N=4096 rows, C=32000 cols, f32.
#define ROWS      4096
#define COLS      32000
#define COLS4     8000          // COLS / 4 (float4 count per row)
#define BLK       1024
#define NWAVES    (BLK / 64)
#define K_ITERS   8             // ceil(COLS4 / BLK)

#define S_SCALE   30.0f
#define COS_M     0.95533648912560601964f   // cos(0.3)
#define SIN_M     0.29552020666133957511f   // sin(0.3)

// Native clang vector type: __builtin_nontemporal_load accepts this
// (HIP_vector_type<float,4> is rejected). Same global_load_dwordx4.
typedef float vfloat4 __attribute__((ext_vector_type(4)));

// One block per row. Row slice lives in registers (8 x vfloat4 per thread):
// pass 1 computes sum(x^2) while loading, pass 2 re-reads registers for
// sum(exp(S*x/norm)). x is read from HBM exactly once, non-temporally.
__global__ __launch_bounds__(BLK)
void arcface_row_kernel(const float* __restrict__ x,
                        const int* __restrict__ target,
                        float* __restrict__ rowL) {
    const int row = blockIdx.x;
    const int tid = threadIdx.x;
    const int lane = tid & 63;
    const int wave = tid >> 6;

    const vfloat4* __restrict__ rowp =
        reinterpret_cast<const vfloat4*>(x + (size_t)row * COLS);

    __shared__ float red[NWAVES];
    __shared__ float s_inv;

    // ---- prefetch the target-column element (hidden under pass 1) ----
    float xt = 0.0f;
    if (tid == 0) {
        const int tgt = target[row];                  // L2/HBM load
        xt = x[(size_t)row * COLS + tgt];             // dependent gather
    }

    // ---- pass 1: load row into registers, accumulate sum of squares ----
    vfloat4 v[K_ITERS];
    float ss = 0.0f;
    #pragma unroll
    for (int k = 0; k < K_ITERS; ++k) {
        const int idx = k * BLK + tid;
        if (idx < COLS4) {
            v[k] = __builtin_nontemporal_load(&rowp[idx]);
            ss += v[k].x * v[k].x + v[k].y * v[k].y
                + v[k].z * v[k].z + v[k].w * v[k].w;
        }
    }

    // block reduce ss
    #pragma unroll
    for (int off = 32; off > 0; off >>= 1) ss += __shfl_down(ss, off, 64);
    if (lane == 0) red[wave] = ss;
    __syncthreads();
    if (tid == 0) {
        float tot = 0.0f;
        #pragma unroll
        for (int w = 0; w < NWAVES; ++w) tot += red[w];
        const float norm = sqrtf(tot);
        s_inv = 1.0f / fmaxf(norm, 1e-12f);
    }
    __syncthreads();
    const float inv = s_inv;
    const float sinv = S_SCALE * inv;

    // ---- pass 2: sum of exp(S * x / norm) from registers ----
    float es = 0.0f;
    #pragma unroll
    for (int k = 0; k < K_ITERS; ++k) {
        const int idx = k * BLK + tid;
        if (idx < COLS4) {
            es += __expf(sinv * v[k].x) + __expf(sinv * v[k].y)
                + __expf(sinv * v[k].z) + __expf(sinv * v[k].w);
        }
    }
    #pragma unroll
    for (int off = 32; off > 0; off >>= 1) es += __shfl_down(es, off, 64);
    if (lane == 0) red[wave] = es;   // ordered vs tid0's reads by barrier above
    __syncthreads();

    if (tid == 0) {
        float row_sum = 0.0f;
        #pragma unroll
        for (int w = 0; w < NWAVES; ++w) row_sum += red[w];

        const float cos_t = xt * inv;

        // numerator = S * cos(acos(clamp(cos_t)) + M), trig-free form
        const float c = fminf(fmaxf(cos_t, -1.0f + 1e-7f), 1.0f - 1e-7f);
        const float sin_t = sqrtf(fmaxf(1.0f - c * c, 0.0f));
        const float numerator = S_SCALE * (c * COS_M - sin_t * SIN_M);

        const float denom = __expf(numerator) + row_sum - __expf(S_SCALE * cos_t);
        rowL[row] = numerator - __logf(denom);
    }
}

// Single-block final reduction: out = -mean(rowL). 1024 thr x 1 float4 each.
__global__ __launch_bounds__(1024)
void arcface_final_kernel(const float* __restrict__ rowL,
                          float* __restrict__ out) {
    __shared__ float red[16];
    const int tid = threadIdx.x;
    const vfloat4 v = reinterpret_cast<const vfloat4*>(rowL)[tid];
    float s = v.x + v.y + v.z + v.w;
    #pragma unroll
    for (int off = 32; off > 0; off >>= 1) s += __shfl_down(s, off, 64);
    if ((tid & 63) == 0) red[tid >> 6] = s;
    __syncthreads();
    if (tid == 0) {
        float tot = 0.0f;
        #pragma unroll
        for (int w = 0; w < 16; ++w) tot += red[w];
        out[0] = -(tot / (float)ROWS);
    }
}

extern "C" void kernel_launch(void* const* d_in, const int* in_sizes, int n_in,
                              void* d_out, int out_size, void* d_ws, size_t ws_size,
                              hipStream_t stream) {
    const float* x      = (const float*)d_in[0];
    const int*   target = (const int*)d_in[1];
    float*       out    = (float*)d_out;
    float*       rowL   = (float*)d_ws;   // ROWS floats = 16 KB scratch

    arcface_row_kernel<<<ROWS, BLK, 0, stream>>>(x, target, rowL);
    arcface_final_kernel<<<1, 1024, 0, stream>>>(rowL, out);
}